// Round 2
// baseline (21919.875 us; speedup 1.0000x reference)
//
#include <hip/hip_runtime.h>

// EncoderDecoder LSTM: B=512, T=512, I=128, H=512.
// R2: single persistent kernel, 256 WGs (8 batch-groups x 32 col-slices).
// Weights in registers (K-split-4 per wave), c in registers, group-local
// barriers via device-scope atomics, h exchanged through global memory with
// agent-scope atomic loads (correct under any WG->XCD mapping).

typedef unsigned short u16;
typedef __bf16 bf16x8 __attribute__((ext_vector_type(8)));
typedef float f32x4 __attribute__((ext_vector_type(4)));
typedef int i32x4 __attribute__((ext_vector_type(4)));

#define H_DIM 512
#define I_DIM 128
#define K_TOT 640
#define NSTEP 1024

__device__ __forceinline__ u16 f2bf(float f) {
  unsigned u = __builtin_bit_cast(unsigned, f);
  u += 0x7fffu + ((u >> 16) & 1u);   // RNE
  return (u16)(u >> 16);
}
__device__ __forceinline__ float sigm(float v) { return 1.0f / (1.0f + __expf(-v)); }
__device__ __forceinline__ float tanh_fast(float v) {
  float e = __expf(-2.0f * fabsf(v));
  float t = (1.0f - e) / (1.0f + e);
  return v < 0.0f ? -t : t;
}
__device__ __forceinline__ bf16x8 ld_frag(const u16* p) {
  i32x4 v = *reinterpret_cast<const i32x4*>(p);
  return __builtin_bit_cast(bf16x8, v);
}

// Wt[n'][k] bf16, n' in [0,2048), k in [0,640): k<512 -> Whh[j][k], else Wih[j][k-512],
// j = (n'&3)*512 + (n'>>2)  (gates interleaved: n' = 4*hcol + gate).
__global__ void prep_w(const float* __restrict__ Whh, const float* __restrict__ Wih,
                       u16* __restrict__ Wt) {
  const int idx = blockIdx.x * 256 + threadIdx.x;
  const int n = idx / K_TOT;
  const int k = idx - n * K_TOT;
  const int j = (n & 3) * 512 + (n >> 2);
  const float v = (k < H_DIM) ? Whh[(size_t)j * H_DIM + k]
                              : Wih[(size_t)j * I_DIM + (k - H_DIM)];
  Wt[idx] = f2bf(v);
}

__global__ void prep_bias(const float* __restrict__ bih, const float* __restrict__ bhh,
                          float* __restrict__ bias) {
  const int n = blockIdx.x * 256 + threadIdx.x;
  const int j = (n & 3) * 512 + (n >> 2);
  bias[n] = bih[j] + bhh[j];
}

__device__ __forceinline__ void load_wf(bf16x8 (&Wf)[5][4], const u16* __restrict__ Wt,
                                        int n0, int lane, int wv) {
#pragma unroll
  for (int ks = 0; ks < 5; ++ks) {
    const int kbase = (ks < 4) ? (wv * 128 + ks * 32) : (512 + wv * 32);
#pragma unroll
    for (int nt = 0; nt < 4; ++nt) {
      const int col = n0 + nt * 16 + (lane & 15);
      Wf[ks][nt] = ld_frag(Wt + (size_t)col * K_TOT + kbase + (lane >> 4) * 8);
    }
  }
}

__device__ __forceinline__ void load_x(f32x4 (&xr)[4][2], const float* __restrict__ x,
                                       int b0, int t, int lane, int wv) {
#pragma unroll
  for (int a = 0; a < 4; ++a) {
    const int row = a * 16 + (lane & 15);
    const float* p = x + ((size_t)(b0 + row) * 512 + t) * 128 + wv * 32 + (lane >> 4) * 8;
    xr[a][0] = *reinterpret_cast<const f32x4*>(p);
    xr[a][1] = *reinterpret_cast<const f32x4*>(p + 4);
  }
}

__device__ __forceinline__ bf16x8 pack_x(const f32x4& x0, const f32x4& x1) {
  union { bf16x8 v; u16 u[8]; } r;
  r.u[0] = f2bf(x0[0]); r.u[1] = f2bf(x0[1]); r.u[2] = f2bf(x0[2]); r.u[3] = f2bf(x0[3]);
  r.u[4] = f2bf(x1[0]); r.u[5] = f2bf(x1[1]); r.u[6] = f2bf(x1[2]); r.u[7] = f2bf(x1[3]);
  return r.v;
}

__global__ __launch_bounds__(256, 1)
void lstm_persist(const u16* __restrict__ encWt, const u16* __restrict__ decWt,
                  const float* __restrict__ encB, const float* __restrict__ decB,
                  const float* __restrict__ x, const float* __restrict__ fcW,
                  const float* __restrict__ fcb, u16* hbuf, float* out, unsigned* cnt)
{
  __shared__ float red[2][64][72];       // 36,864 B, col-major [slot][col][row] pad-72
  __shared__ char lds_pad[48 * 1024];    // forces 1 WG/CU (total LDS > 80KB)

  const int tid  = threadIdx.x;
  const int lane = tid & 63;
  const int wv   = tid >> 6;
  const int g     = blockIdx.x & 7;      // batch group (XCD round-robin heuristic)
  const int slice = blockIdx.x >> 3;     // gate-col slice
  const int n0  = slice * 64;
  const int hc0 = slice * 16;
  const int b0  = g * 64;
  const int er    = tid >> 2;            // epilogue row 0..63
  const int ebase = tid & 3;             // epilogue hcol base (hl = ebase + 4j)

  if (blockIdx.x > 10000) {              // never true: keeps lds_pad allocated
    ((volatile char*)lds_pad)[tid] = 1;
  }

  // Encoder weights + bias into registers (decoder reloaded at s==512).
  bf16x8 Wf[5][4];
  load_wf(Wf, encWt, n0, lane, wv);
  f32x4 bsv[4];
#pragma unroll
  for (int j = 0; j < 4; ++j)
    bsv[j] = *reinterpret_cast<const f32x4*>(encB + n0 + (ebase + 4 * j) * 4);

  float cc[4] = {0.f, 0.f, 0.f, 0.f};    // c cells live in registers (persistent mapping)

  f32x4 xr[4][2];
  load_x(xr, x, b0, 0, lane, wv);        // prefetch x for step 0

  const int colR = lane & 15;
  const int row4 = (lane >> 4) * 4;

  for (int s = 0; s < NSTEP; ++s) {
    if (s == 512) {                      // enc -> dec switch (uniform, once)
      load_wf(Wf, decWt, n0, lane, wv);
#pragma unroll
      for (int j = 0; j < 4; ++j)
        bsv[j] = *reinterpret_cast<const f32x4*>(decB + n0 + (ebase + 4 * j) * 4);
    }

    // Convert prefetched x to bf16 MFMA A-frags.
    bf16x8 xa[4];
#pragma unroll
    for (int a = 0; a < 4; ++a) xa[a] = pack_x(xr[a][0], xr[a][1]);

    // ---- K loop: load ALL h frags (agent-scope atomic dwords), then MFMA ----
    const int* h32 = (const int*)(hbuf + ((size_t)(s & 1) * 8 + g) * (64 * H_DIM));
    bf16x8 af[4][4];                     // [kk][a]
#pragma unroll
    for (int kk = 0; kk < 4; ++kk) {
#pragma unroll
      for (int a = 0; a < 4; ++a) {
        const int row = a * 16 + (lane & 15);
        const int dw = (row * H_DIM + wv * 128 + kk * 32 + (lane >> 4) * 8) >> 1;
        i32x4 v;
#pragma unroll
        for (int d = 0; d < 4; ++d)
          v[d] = __hip_atomic_load((int*)(h32 + dw + d), __ATOMIC_RELAXED,
                                   __HIP_MEMORY_SCOPE_AGENT);
        af[kk][a] = __builtin_bit_cast(bf16x8, v);
      }
    }
    f32x4 acc[4][4] = {};
#pragma unroll
    for (int kk = 0; kk < 4; ++kk)
#pragma unroll
      for (int a = 0; a < 4; ++a)
#pragma unroll
        for (int nt = 0; nt < 4; ++nt)
          acc[a][nt] = __builtin_amdgcn_mfma_f32_16x16x32_bf16(af[kk][a], Wf[kk][nt],
                                                               acc[a][nt], 0, 0, 0);
#pragma unroll
    for (int a = 0; a < 4; ++a)
#pragma unroll
      for (int nt = 0; nt < 4; ++nt)
        acc[a][nt] = __builtin_amdgcn_mfma_f32_16x16x32_bf16(xa[a], Wf[4][nt],
                                                             acc[a][nt], 0, 0, 0);

    // ---- K-split reduction: pairwise through LDS (slot = wv>>1) ----
    if (wv & 1) {
#pragma unroll
      for (int a = 0; a < 4; ++a)
#pragma unroll
        for (int nt = 0; nt < 4; ++nt)
          *reinterpret_cast<f32x4*>(&red[wv >> 1][nt * 16 + colR][a * 16 + row4]) = acc[a][nt];
    }
    __syncthreads();
    if (!(wv & 1)) {
#pragma unroll
      for (int a = 0; a < 4; ++a)
#pragma unroll
        for (int nt = 0; nt < 4; ++nt)
          acc[a][nt] += *reinterpret_cast<const f32x4*>(&red[wv >> 1][nt * 16 + colR][a * 16 + row4]);
    }
    if (wv == 2) {
#pragma unroll
      for (int a = 0; a < 4; ++a)
#pragma unroll
        for (int nt = 0; nt < 4; ++nt)
          *reinterpret_cast<f32x4*>(&red[1][nt * 16 + colR][a * 16 + row4]) = acc[a][nt];
    }
    __syncthreads();
    if (wv == 0) {
#pragma unroll
      for (int a = 0; a < 4; ++a)
#pragma unroll
        for (int nt = 0; nt < 4; ++nt) {
          acc[a][nt] += *reinterpret_cast<const f32x4*>(&red[1][nt * 16 + colR][a * 16 + row4]);
          *reinterpret_cast<f32x4*>(&red[0][nt * 16 + colR][a * 16 + row4]) = acc[a][nt];
        }
    }
    __syncthreads();

    // ---- epilogue: all 256 threads, 4 cells each (row=er, hcol=hc0+ebase+4j) ----
    float hc4[4];
#pragma unroll
    for (int j = 0; j < 4; ++j) {
      const int hl = ebase + 4 * j;
      const float v0 = red[0][hl * 4 + 0][er] + bsv[j][0];
      const float v1 = red[0][hl * 4 + 1][er] + bsv[j][1];
      const float v2 = red[0][hl * 4 + 2][er] + bsv[j][2];
      const float v3 = red[0][hl * 4 + 3][er] + bsv[j][3];
      const float iv = sigm(v0);
      const float fv = sigm(v1);
      const float gv = tanh_fast(v2);
      const float ov = sigm(v3);
      const float cn = fv * cc[j] + iv * gv;
      cc[j] = cn;
      hc4[j] = ov * tanh_fast(cn);
    }

    if (s < NSTEP - 1) {
      u16* hd = hbuf + ((size_t)((s + 1) & 1) * 8 + g) * (64 * H_DIM);
#pragma unroll
      for (int j = 0; j < 4; ++j)
        hd[er * H_DIM + hc0 + ebase + 4 * j] = f2bf(hc4[j]);
      load_x(xr, x, b0, (s + 1) & 511, lane, wv);   // prefetch x under barrier wait
      __syncthreads();                               // drains vmcnt: h stores at L2
      if (tid == 0) {
        __hip_atomic_fetch_add(cnt + g, 1u, __ATOMIC_RELEASE, __HIP_MEMORY_SCOPE_AGENT);
        const unsigned target = 32u * (unsigned)(s + 1);
        while (__hip_atomic_load(cnt + g, __ATOMIC_RELAXED, __HIP_MEMORY_SCOPE_AGENT) < target)
          __builtin_amdgcn_s_sleep(2);
      }
      __syncthreads();
    } else {
      // fc on last decoder h: out[b] = sum_h h*fcW[h] + fcb
      float p = 0.f;
#pragma unroll
      for (int j = 0; j < 4; ++j) p += hc4[j] * fcW[hc0 + ebase + 4 * j];
      p += __shfl_xor(p, 1);
      p += __shfl_xor(p, 2);
      if (ebase == 0) {
        if (slice == 0) p += fcb[0];
        atomicAdd(out + b0 + er, p);
      }
    }
  }
}

extern "C" void kernel_launch(void* const* d_in, const int* in_sizes, int n_in,
                              void* d_out, int out_size, void* d_ws, size_t ws_size,
                              hipStream_t stream) {
  const float* x       = (const float*)d_in[0];
  const float* enc_Wih = (const float*)d_in[1];
  const float* enc_Whh = (const float*)d_in[2];
  const float* enc_bih = (const float*)d_in[3];
  const float* enc_bhh = (const float*)d_in[4];
  const float* dec_Wih = (const float*)d_in[5];
  const float* dec_Whh = (const float*)d_in[6];
  const float* dec_bih = (const float*)d_in[7];
  const float* dec_bhh = (const float*)d_in[8];
  const float* fc_W    = (const float*)d_in[9];
  const float* fc_b    = (const float*)d_in[10];
  float* out = (float*)d_out;

  // ws carve (~6.3 MB)
  char* ws = (char*)d_ws;
  u16*   encWt   = (u16*)ws;   ws += (size_t)2048 * K_TOT * 2;
  u16*   decWt   = (u16*)ws;   ws += (size_t)2048 * K_TOT * 2;
  float* encBias = (float*)ws; ws += 2048 * 4;
  float* decBias = (float*)ws; ws += 2048 * 4;
  u16*   hbuf    = (u16*)ws;   ws += (size_t)2 * 8 * 64 * H_DIM * 2;
  unsigned* cnt  = (unsigned*)ws; ws += 256;

  prep_w<<<(2048 * K_TOT) / 256, 256, 0, stream>>>(enc_Whh, enc_Wih, encWt);
  prep_w<<<(2048 * K_TOT) / 256, 256, 0, stream>>>(dec_Whh, dec_Wih, decWt);
  prep_bias<<<2048 / 256, 256, 0, stream>>>(enc_bih, enc_bhh, encBias);
  prep_bias<<<2048 / 256, 256, 0, stream>>>(dec_bih, dec_bhh, decBias);

  // zero: h parity-0 buffer, barrier counters, output (ws/d_out are re-poisoned).
  hipMemsetAsync(hbuf, 0, (size_t)8 * 64 * H_DIM * 2, stream);
  hipMemsetAsync(cnt, 0, 256, stream);
  hipMemsetAsync(out, 0, 512 * 4, stream);

  lstm_persist<<<256, 256, 0, stream>>>(encWt, decWt, encBias, decBias, x,
                                        fc_W, fc_b, hbuf, out, cnt);
}

// Round 3
// 12434.748 us; speedup vs baseline: 1.7628x; 1.7628x over previous
//
#include <hip/hip_runtime.h>

// EncoderDecoder LSTM: B=512, T=512, I=128, H=512.
// R3: persistent kernel, 32 batch-groups x 8 WGs (grid 256 = #CUs).
// - Weights as MFMA *A* operand => acc regs hold (i,f,g,o) quadruple per lane:
//   no K-split, no LDS reduction/transpose.
// - Per-WG padded release flags (monotonic step counters), 8-participant barrier.
// - h exchanged via global bf16 + relaxed agent-scope u64 atomic loads (bypass
//   stale L1/L2); producer visibility via release fetch_add (emits L2 writeback).
// - h-part weights (16 kk-frags x 4 col-tiles) in 256 VGPRs; x-part in 64KB LDS.

typedef unsigned short u16;
typedef unsigned long long u64;
typedef __bf16 bf16x8 __attribute__((ext_vector_type(8)));
typedef float f32x4 __attribute__((ext_vector_type(4)));
typedef int i32x4 __attribute__((ext_vector_type(4)));

#define H_DIM 512
#define I_DIM 128
#define K_TOT 640
#define NSTEP 1024
#define NGRP  32
#define ROWS  16

__device__ __forceinline__ u16 f2bf(float f) {
  unsigned u = __builtin_bit_cast(unsigned, f);
  u += 0x7fffu + ((u >> 16) & 1u);   // RNE
  return (u16)(u >> 16);
}
__device__ __forceinline__ float sigm(float v) { return 1.0f / (1.0f + __expf(-v)); }
__device__ __forceinline__ float tanh_fast(float v) {
  float e = __expf(-2.0f * fabsf(v));
  float t = (1.0f - e) / (1.0f + e);
  return v < 0.0f ? -t : t;
}
__device__ __forceinline__ bf16x8 ld_frag(const u16* p) {
  i32x4 v = *reinterpret_cast<const i32x4*>(p);
  return __builtin_bit_cast(bf16x8, v);
}
__device__ __forceinline__ bf16x8 pack_x(const f32x4& x0, const f32x4& x1) {
  union { bf16x8 v; u16 u[8]; } r;
  r.u[0] = f2bf(x0[0]); r.u[1] = f2bf(x0[1]); r.u[2] = f2bf(x0[2]); r.u[3] = f2bf(x0[3]);
  r.u[4] = f2bf(x1[0]); r.u[5] = f2bf(x1[1]); r.u[6] = f2bf(x1[2]); r.u[7] = f2bf(x1[3]);
  return r.v;
}

// Wt[n'][k] bf16: k<512 -> Whh[j][k], else Wih[j][k-512]; j=(n'&3)*512+(n'>>2)
// (gates interleaved: n' = 4*hcol + gate).
__global__ void prep_w(const float* __restrict__ Whh, const float* __restrict__ Wih,
                       u16* __restrict__ Wt) {
  const int idx = blockIdx.x * 256 + threadIdx.x;
  const int n = idx / K_TOT;
  const int k = idx - n * K_TOT;
  const int j = (n & 3) * 512 + (n >> 2);
  const float v = (k < H_DIM) ? Whh[(size_t)j * H_DIM + k]
                              : Wih[(size_t)j * I_DIM + (k - H_DIM)];
  Wt[idx] = f2bf(v);
}

__global__ void prep_bias(const float* __restrict__ bih, const float* __restrict__ bhh,
                          float* __restrict__ bias) {
  const int n = blockIdx.x * 256 + threadIdx.x;
  const int j = (n & 3) * 512 + (n >> 2);
  bias[n] = bih[j] + bhh[j];
}

__global__ __launch_bounds__(256, 1)
void lstm_persist(const u16* __restrict__ encWt, const u16* __restrict__ decWt,
                  const float* __restrict__ encB, const float* __restrict__ decB,
                  const float* __restrict__ x, const float* __restrict__ fcW,
                  const float* __restrict__ fcb, u16* __restrict__ hbuf,
                  float* out, unsigned* flags)
{
  __shared__ u16 wxl[4][16][64 * 8];   // 64 KB: x-part weight frags, per-wave regions
  __shared__ float bias_l[256];

  const int tid  = threadIdx.x;
  const int lane = tid & 63;
  const int wv   = tid >> 6;
  const int g    = blockIdx.x & 31;    // group: 8 WGs {g+32q} -> same XCD (g&7) if round-robin
  const int q    = blockIdx.x >> 5;    // WG-within-group 0..7
  const int row  = lane & 15;
  const int quad = lane >> 4;
  const int n0   = q * 256 + wv * 64;  // wave's gate-col base
  const int hc0  = n0 >> 2;            // wave's h-col base
  const int b0   = g * ROWS;

  bf16x8 Wf[16][4];                    // h-part weights: A-frags [kk][nt], 256 VGPR
  auto stage = [&](const u16* Wt, const float* biasG) {
#pragma unroll
    for (int kk = 0; kk < 16; ++kk)
#pragma unroll
      for (int nt = 0; nt < 4; ++nt)
        Wf[kk][nt] = ld_frag(Wt + (size_t)(n0 + nt * 16 + row) * K_TOT + kk * 32 + quad * 8);
#pragma unroll
    for (int kk = 0; kk < 4; ++kk)
#pragma unroll
      for (int nt = 0; nt < 4; ++nt)
        *reinterpret_cast<i32x4*>(&wxl[wv][kk * 4 + nt][lane * 8]) =
            *reinterpret_cast<const i32x4*>(
                Wt + (size_t)(n0 + nt * 16 + row) * K_TOT + 512 + kk * 32 + quad * 8);
    bias_l[tid] = biasG[q * 256 + tid];
    __syncthreads();
  };
  stage(encWt, encB);

  float cc[4] = {0.f, 0.f, 0.f, 0.f};  // c cells: row=lane&15, hcol=hc0+nt*4+quad

  // x prefetch+pack for step 0
  f32x4 xr[4][2];
  bf16x8 xa[4];
  {
    const float* xp = x + ((size_t)(b0 + row) * 512 + 0) * 128 + quad * 8;
#pragma unroll
    for (int kk = 0; kk < 4; ++kk) {
      xr[kk][0] = *reinterpret_cast<const f32x4*>(xp + kk * 32);
      xr[kk][1] = *reinterpret_cast<const f32x4*>(xp + kk * 32 + 4);
    }
#pragma unroll
    for (int kk = 0; kk < 4; ++kk) xa[kk] = pack_x(xr[kk][0], xr[kk][1]);
  }

#pragma clang loop unroll(disable)
  for (int s = 0; s < NSTEP; ++s) {
    if (s == 512) stage(decWt, decB);  // enc -> dec (uniform, once)

    // ---- h loads: B-frags [n=row][k=quad*8+j], relaxed agent atomics ----
    const u64* hp = (const u64*)(hbuf + (size_t)((s & 1) * NGRP + g) * (ROWS * H_DIM));
    const int hbase = row * (H_DIM / 4) + quad * 2;   // u64 units
    bf16x8 hf[16];
#pragma unroll
    for (int kk = 0; kk < 16; ++kk) {
      union { u64 v[2]; bf16x8 f; } tmp;
      tmp.v[0] = __hip_atomic_load(hp + hbase + kk * 8,     __ATOMIC_RELAXED,
                                   __HIP_MEMORY_SCOPE_AGENT);
      tmp.v[1] = __hip_atomic_load(hp + hbase + kk * 8 + 1, __ATOMIC_RELAXED,
                                   __HIP_MEMORY_SCOPE_AGENT);
      hf[kk] = tmp.f;
    }

    // ---- x prefetch for next step (plain loads; x is read-only) ----
    {
      const int t2 = (s + 1) & 511;
      const float* xp = x + ((size_t)(b0 + row) * 512 + t2) * 128 + quad * 8;
#pragma unroll
      for (int kk = 0; kk < 4; ++kk) {
        xr[kk][0] = *reinterpret_cast<const f32x4*>(xp + kk * 32);
        xr[kk][1] = *reinterpret_cast<const f32x4*>(xp + kk * 32 + 4);
      }
    }

    // ---- gates GEMM: D[m=gate][n=batch row]; x-part first (hides h latency) ----
    f32x4 acc[4] = {};
#pragma unroll
    for (int kk = 0; kk < 4; ++kk)
#pragma unroll
      for (int nt = 0; nt < 4; ++nt) {
        bf16x8 wf = ld_frag(&wxl[wv][kk * 4 + nt][lane * 8]);
        acc[nt] = __builtin_amdgcn_mfma_f32_16x16x32_bf16(wf, xa[kk], acc[nt], 0, 0, 0);
      }
#pragma unroll
    for (int kk = 0; kk < 16; ++kk)
#pragma unroll
      for (int nt = 0; nt < 4; ++nt)
        acc[nt] = __builtin_amdgcn_mfma_f32_16x16x32_bf16(Wf[kk][nt], hf[kk], acc[nt], 0, 0, 0);

    // ---- epilogue: acc[nt] = (i,f,g,o) for row=lane&15, hcol=hc0+nt*4+quad ----
    float hv[4];
#pragma unroll
    for (int nt = 0; nt < 4; ++nt) {
      f32x4 b4 = *reinterpret_cast<const f32x4*>(&bias_l[wv * 64 + nt * 16 + quad * 4]);
      const float iv = sigm(acc[nt][0] + b4[0]);
      const float fv = sigm(acc[nt][1] + b4[1]);
      const float gv = tanh_fast(acc[nt][2] + b4[2]);
      const float ov = sigm(acc[nt][3] + b4[3]);
      const float cn = fv * cc[nt] + iv * gv;
      cc[nt] = cn;
      hv[nt] = ov * tanh_fast(cn);
    }

    if (s < NSTEP - 1) {
      u16* hd = hbuf + (size_t)(((s + 1) & 1) * NGRP + g) * (ROWS * H_DIM);
#pragma unroll
      for (int nt = 0; nt < 4; ++nt)
        hd[row * H_DIM + hc0 + nt * 4 + quad] = f2bf(hv[nt]);
      // pack next x while stores drain
#pragma unroll
      for (int kk = 0; kk < 4; ++kk) xa[kk] = pack_x(xr[kk][0], xr[kk][1]);
      __syncthreads();                              // all waves' h stores in L2
      if (tid == 0) {
        // release fetch_add: L2 writeback + flag to coherence point (R2-validated)
        __hip_atomic_fetch_add(flags + g * 64 + q * 8, 1u, __ATOMIC_RELEASE,
                               __HIP_MEMORY_SCOPE_AGENT);
        const unsigned tgt = (unsigned)(s + 1);
        for (;;) {
          unsigned mn = 0xffffffffu;
#pragma unroll
          for (int j = 0; j < 8; ++j) {
            unsigned v = __hip_atomic_load(flags + g * 64 + j * 8, __ATOMIC_RELAXED,
                                           __HIP_MEMORY_SCOPE_AGENT);
            mn = v < mn ? v : mn;
          }
          if (mn >= tgt) break;
          __builtin_amdgcn_s_sleep(1);
        }
      }
      __syncthreads();
    } else {
      // fc on last decoder h: out[b] = sum_h h*fcW[h] + fcb
      float p = 0.f;
#pragma unroll
      for (int nt = 0; nt < 4; ++nt) p += hv[nt] * fcW[hc0 + nt * 4 + quad];
      p += __shfl_xor(p, 16);
      p += __shfl_xor(p, 32);
      if (lane < 16) {
        if (q == 0 && wv == 0) p += fcb[0];
        atomicAdd(out + b0 + lane, p);
      }
    }
  }
}

extern "C" void kernel_launch(void* const* d_in, const int* in_sizes, int n_in,
                              void* d_out, int out_size, void* d_ws, size_t ws_size,
                              hipStream_t stream) {
  const float* x       = (const float*)d_in[0];
  const float* enc_Wih = (const float*)d_in[1];
  const float* enc_Whh = (const float*)d_in[2];
  const float* enc_bih = (const float*)d_in[3];
  const float* enc_bhh = (const float*)d_in[4];
  const float* dec_Wih = (const float*)d_in[5];
  const float* dec_Whh = (const float*)d_in[6];
  const float* dec_bih = (const float*)d_in[7];
  const float* dec_bhh = (const float*)d_in[8];
  const float* fc_W    = (const float*)d_in[9];
  const float* fc_b    = (const float*)d_in[10];
  float* out = (float*)d_out;

  // ws carve (~6.3 MB)
  char* ws = (char*)d_ws;
  u16*   encWt   = (u16*)ws;   ws += (size_t)2048 * K_TOT * 2;
  u16*   decWt   = (u16*)ws;   ws += (size_t)2048 * K_TOT * 2;
  float* encBias = (float*)ws; ws += 2048 * 4;
  float* decBias = (float*)ws; ws += 2048 * 4;
  u16*   hbuf    = (u16*)ws;   ws += (size_t)2 * NGRP * ROWS * H_DIM * 2;
  unsigned* flags = (unsigned*)ws; ws += NGRP * 64 * 4;   // 256B per group

  prep_w<<<(2048 * K_TOT) / 256, 256, 0, stream>>>(enc_Whh, enc_Wih, encWt);
  prep_w<<<(2048 * K_TOT) / 256, 256, 0, stream>>>(dec_Whh, dec_Wih, decWt);
  prep_bias<<<2048 / 256, 256, 0, stream>>>(enc_bih, enc_bhh, encBias);
  prep_bias<<<2048 / 256, 256, 0, stream>>>(dec_bih, dec_bhh, decBias);

  hipMemsetAsync(hbuf, 0, (size_t)NGRP * ROWS * H_DIM * 2, stream);  // h parity-0 = 0
  hipMemsetAsync(flags, 0, NGRP * 64 * 4, stream);
  hipMemsetAsync(out, 0, 512 * 4, stream);

  lstm_persist<<<256, 256, 0, stream>>>(encWt, decWt, encBias, decBias, x,
                                        fc_W, fc_b, hbuf, out, flags);
}